// Round 3
// baseline (354.596 us; speedup 1.0000x reference)
//
#include <hip/hip_runtime.h>
#include <math.h>

#define B_ 32
#define S_ 1024
#define H_ 512
#define K_ 1024                 // 2*H
#define M_ (B_ * S_)            // 32768

typedef __attribute__((ext_vector_type(8))) short bf16x8;
typedef __attribute__((ext_vector_type(4))) float f32x4;

// RNE split: f = hi + lo with hi,lo bf16; dropped cross-term ~2^-18 relative
__device__ __forceinline__ void split_bf16(float f, unsigned short& hi, unsigned short& lo) {
    unsigned u = __float_as_uint(f);
    unsigned rh = (u + 0x7fffu + ((u >> 16) & 1u)) >> 16;
    hi = (unsigned short)rh;
    float fh = __uint_as_float(rh << 16);
    float r = f - fh;                      // exact (Veltkamp-style split)
    unsigned ur = __float_as_uint(r);
    unsigned rl = (ur + 0x7fffu + ((ur >> 16) & 1u)) >> 16;
    lo = (unsigned short)rl;
}

// async 16B global -> LDS (lane i lands at lds_base + i*16; lds_base wave-uniform)
__device__ __forceinline__ void async_copy16(const void* g, void* l) {
    __builtin_amdgcn_global_load_lds(
        (const __attribute__((address_space(1))) void*)g,
        (__attribute__((address_space(3))) void*)l, 16, 0, 0);
}

// ---------------------------------------------------------------------------
// Kernel 0: split EO (M*K fp32) -> EOh/EOl (bf16). Memory-bound, ~268 MB.
// ---------------------------------------------------------------------------
__global__ __launch_bounds__(256) void split_eo_kernel(
    const float* __restrict__ EO, unsigned short* __restrict__ EOh,
    unsigned short* __restrict__ EOl)
{
    const size_t i = ((size_t)blockIdx.x * 256 + threadIdx.x) * 8;
    const float4 a = *reinterpret_cast<const float4*>(EO + i);
    const float4 b = *reinterpret_cast<const float4*>(EO + i + 4);
    union { unsigned short us[8]; uint4 u4; } h, l;
    split_bf16(a.x, h.us[0], l.us[0]);
    split_bf16(a.y, h.us[1], l.us[1]);
    split_bf16(a.z, h.us[2], l.us[2]);
    split_bf16(a.w, h.us[3], l.us[3]);
    split_bf16(b.x, h.us[4], l.us[4]);
    split_bf16(b.y, h.us[5], l.us[5]);
    split_bf16(b.z, h.us[6], l.us[6]);
    split_bf16(b.w, h.us[7], l.us[7]);
    *reinterpret_cast<uint4*>(EOh + i) = h.u4;
    *reinterpret_cast<uint4*>(EOl + i) = l.u4;
}

// ---------------------------------------------------------------------------
// Kernel 1: hb[b][h] = sum_k hidden[b][k]*W[k][h] + bias[h]
// ---------------------------------------------------------------------------
__global__ __launch_bounds__(256) void hproj_kernel(
    const float* __restrict__ hidden, const float* __restrict__ W,
    const float* __restrict__ bias, float* __restrict__ hb)
{
    const int tid = threadIdx.x;
    const int h0  = blockIdx.x * 64;
    const int b   = blockIdx.y;
    const int h   = h0 + (tid & 63);
    const int ks  = tid >> 6;              // 4 k-slices of 128
    const float* hrow = hidden + b * H_;
    float acc = 0.f;
    #pragma unroll 8
    for (int k = ks * 128; k < ks * 128 + 128; ++k)
        acc = fmaf(hrow[k], W[(size_t)k * H_ + h], acc);
    __shared__ float red[4][64];
    red[ks][tid & 63] = acc;
    __syncthreads();
    if (tid < 64)
        hb[b * H_ + h0 + tid] = red[0][tid] + red[1][tid] + red[2][tid] + red[3][tid]
                              + bias[h0 + tid];
}

// ---------------------------------------------------------------------------
// Kernel 1b: transpose + bf16-split We (K x 512) -> Wth/Wtl (512 x K)
// ---------------------------------------------------------------------------
__global__ __launch_bounds__(256) void conv_we_kernel(
    const float* __restrict__ We, unsigned short* __restrict__ Wh,
    unsigned short* __restrict__ Wl)
{
    __shared__ float t[32][33];
    const int tx = threadIdx.x & 31, ty = threadIdx.x >> 5;   // ty 0..7
    const int k0 = blockIdx.x * 32, n0 = blockIdx.y * 32;
    #pragma unroll
    for (int j = 0; j < 4; ++j) {
        const int k = ty + 8 * j;
        t[k][tx] = We[(size_t)(k0 + k) * H_ + n0 + tx];
    }
    __syncthreads();
    #pragma unroll
    for (int j = 0; j < 4; ++j) {
        const int n = ty + 8 * j;
        unsigned short hi, lo;
        split_bf16(t[tx][n], hi, lo);
        Wh[(size_t)(n0 + n) * K_ + k0 + tx] = hi;
        Wl[(size_t)(n0 + n) * K_ + k0 + tx] = lo;
    }
}

// ---------------------------------------------------------------------------
// Kernel 2: MFMA GEMM from pre-split bf16, global_load_lds staging.
//   Block 128x128, BK=32, 4 waves of 64x64, 16x16x32 bf16 MFMA x3 (split).
//   LDS tiles unpadded [row][32k], 64B rows; XOR quarter swizzle
//   slot = quad ^ ((row>>1)&3) applied on the GLOBAL side at staging so
//   ds_read_b128 fragment reads are exactly 2-way (free).
// ---------------------------------------------------------------------------
__global__ __launch_bounds__(256, 3) void gemm_mfma_pre(
    const unsigned short* __restrict__ EOh, const unsigned short* __restrict__ EOl,
    const unsigned short* __restrict__ Bth, const unsigned short* __restrict__ Btl,
    const float* __restrict__ hb, const float* __restrict__ v,
    float* __restrict__ partial)
{
    __shared__ unsigned short lds[4 * 128 * 32];   // Ah | Al | Bh | Bl, 8KB each
    unsigned short* Ah = lds;
    unsigned short* Al = lds + 4096;
    unsigned short* Bh = lds + 8192;
    unsigned short* Bl = lds + 12288;

    const int tid  = threadIdx.x;
    const int nt   = blockIdx.x;              // 0..3 fastest: A L2/L3 sharing
    const int mt   = blockIdx.y;              // 0..255
    const int row0 = mt * 128;
    const int col0 = nt * 128;
    const int batch = row0 >> 10;

    const int lane   = tid & 63;
    const int wave   = tid >> 6;
    const int wm     = wave >> 1, wn = wave & 1;
    const int lanelo = lane & 15, quad = lane >> 4;

    // staging geometry: issue = 16 rows x 64B = 1KB; wave w does issues 2w,2w+1
    const int rl = lane >> 2;                 // row within issue (0..15)
    const int qs = lane & 3;                  // LDS quarter slot (16B units)

    // per-lane global element offsets (advance by 32 per k-step)
    size_t ga[2], gb[2];
    int ldsoff[2];
    #pragma unroll
    for (int j = 0; j < 2; ++j) {
        const int iss = wave * 2 + j;
        const int r   = iss * 16 + rl;        // tile row 0..127
        const int qg  = qs ^ ((r >> 1) & 3);  // swizzled global quarter
        ga[j] = (size_t)(row0 + r) * K_ + qg * 8;
        gb[j] = (size_t)(col0 + r) * K_ + qg * 8;
        ldsoff[j] = iss * 512;                // shorts (1KB per issue)
    }

    f32x4 acc[4][4];
    #pragma unroll
    for (int i = 0; i < 4; ++i)
        #pragma unroll
        for (int j = 0; j < 4; ++j)
            acc[i][j] = (f32x4){0.f, 0.f, 0.f, 0.f};

    for (int k0 = 0; k0 < K_; k0 += 32) {
        #pragma unroll
        for (int j = 0; j < 2; ++j) {
            async_copy16(EOh + ga[j] + k0, Ah + ldsoff[j]);
            async_copy16(EOl + ga[j] + k0, Al + ldsoff[j]);
            async_copy16(Bth + gb[j] + k0, Bh + ldsoff[j]);
            async_copy16(Btl + gb[j] + k0, Bl + ldsoff[j]);
        }
        __syncthreads();

        bf16x8 a_h[4], a_l[4], b_h[4], b_l[4];
        #pragma unroll
        for (int fi = 0; fi < 4; ++fi) {
            const int m  = wm * 64 + fi * 16 + lanelo;
            const int sa = quad ^ ((m >> 1) & 3);
            a_h[fi] = *reinterpret_cast<const bf16x8*>(&Ah[m * 32 + sa * 8]);
            a_l[fi] = *reinterpret_cast<const bf16x8*>(&Al[m * 32 + sa * 8]);
            const int n  = wn * 64 + fi * 16 + lanelo;
            const int sb = quad ^ ((n >> 1) & 3);
            b_h[fi] = *reinterpret_cast<const bf16x8*>(&Bh[n * 32 + sb * 8]);
            b_l[fi] = *reinterpret_cast<const bf16x8*>(&Bl[n * 32 + sb * 8]);
        }
        #pragma unroll
        for (int fi = 0; fi < 4; ++fi)
            #pragma unroll
            for (int fj = 0; fj < 4; ++fj) {
                acc[fi][fj] = __builtin_amdgcn_mfma_f32_16x16x32_bf16(
                    a_h[fi], b_h[fj], acc[fi][fj], 0, 0, 0);
                acc[fi][fj] = __builtin_amdgcn_mfma_f32_16x16x32_bf16(
                    a_h[fi], b_l[fj], acc[fi][fj], 0, 0, 0);
                acc[fi][fj] = __builtin_amdgcn_mfma_f32_16x16x32_bf16(
                    a_l[fi], b_h[fj], acc[fi][fj], 0, 0, 0);
            }
        __syncthreads();
    }

    // ---- epilogue: tanh(acc + hb)*v, reduce over this block's 128 cols ----
    const float* hb_row = hb + batch * H_;
    float hbv[4], vv[4];
    #pragma unroll
    for (int fj = 0; fj < 4; ++fj) {
        const int c = col0 + wn * 64 + fj * 16 + lanelo;
        hbv[fj] = hb_row[c];
        vv[fj]  = v[c];
    }
    float* red = reinterpret_cast<float*>(lds);   // 256 floats, reuse LDS
    #pragma unroll
    for (int fi = 0; fi < 4; ++fi)
        #pragma unroll
        for (int r = 0; r < 4; ++r) {
            float rs = 0.f;
            #pragma unroll
            for (int fj = 0; fj < 4; ++fj)
                rs = fmaf(tanhf(acc[fi][fj][r] + hbv[fj]), vv[fj], rs);
            rs += __shfl_xor(rs, 1, 64);
            rs += __shfl_xor(rs, 2, 64);
            rs += __shfl_xor(rs, 4, 64);
            rs += __shfl_xor(rs, 8, 64);
            if (lanelo == 0) {
                const int row = wm * 64 + fi * 16 + quad * 4 + r;
                red[row * 2 + wn] = rs;
            }
        }
    __syncthreads();
    if (tid < 128)
        partial[(size_t)nt * M_ + row0 + tid] = red[tid * 2] + red[tid * 2 + 1];
}

// ---------------------------------------------------------------------------
// Fallback: round-2 MFMA GEMM with in-kernel A split (if ws too small)
// ---------------------------------------------------------------------------
#define AST 40
__global__ __launch_bounds__(256, 3) void fused_attn_gemm_mfma(
    const float* __restrict__ EO, const unsigned short* __restrict__ Bth,
    const unsigned short* __restrict__ Btl, const float* __restrict__ hb,
    const float* __restrict__ v, float* __restrict__ partial)
{
    __shared__ unsigned short Ah[128 * AST];
    __shared__ unsigned short Al[128 * AST];
    __shared__ unsigned short Bh[128 * AST];
    __shared__ unsigned short Bl[128 * AST];
    const int tid  = threadIdx.x;
    const int nt   = blockIdx.x;
    const int mt   = blockIdx.y;
    const int row0 = mt * 128, col0 = nt * 128;
    const int batch = row0 >> 10;
    const int lane = tid & 63, wave = tid >> 6;
    const int wm = wave >> 1, wn = wave & 1;
    const int lanelo = lane & 15, quad = lane >> 4;
    f32x4 acc[4][4];
    #pragma unroll
    for (int i = 0; i < 4; ++i)
        #pragma unroll
        for (int j = 0; j < 4; ++j) acc[i][j] = (f32x4){0.f, 0.f, 0.f, 0.f};
    for (int k0 = 0; k0 < K_; k0 += 32) {
        #pragma unroll
        for (int q = 0; q < 4; ++q) {
            const int f = tid + 256 * q;
            const int m = f >> 3, c = f & 7;
            const float4 av = *reinterpret_cast<const float4*>(
                EO + (size_t)(row0 + m) * K_ + k0 + c * 4);
            union { unsigned short us[4]; uint2 u2; } ph, pl;
            split_bf16(av.x, ph.us[0], pl.us[0]);
            split_bf16(av.y, ph.us[1], pl.us[1]);
            split_bf16(av.z, ph.us[2], pl.us[2]);
            split_bf16(av.w, ph.us[3], pl.us[3]);
            *reinterpret_cast<uint2*>(&Ah[m * AST + c * 4]) = ph.u2;
            *reinterpret_cast<uint2*>(&Al[m * AST + c * 4]) = pl.u2;
        }
        #pragma unroll
        for (int q = 0; q < 2; ++q) {
            const int s = tid + 256 * q;
            const int n = s >> 2, qq = s & 3;
            const size_t g = (size_t)(col0 + n) * K_ + k0 + qq * 8;
            *reinterpret_cast<uint4*>(&Bh[n * AST + qq * 8]) =
                *reinterpret_cast<const uint4*>(Bth + g);
            *reinterpret_cast<uint4*>(&Bl[n * AST + qq * 8]) =
                *reinterpret_cast<const uint4*>(Btl + g);
        }
        __syncthreads();
        bf16x8 a_h[4], a_l[4], b_h[4], b_l[4];
        #pragma unroll
        for (int fi = 0; fi < 4; ++fi) {
            const int m = wm * 64 + fi * 16 + lanelo;
            a_h[fi] = *reinterpret_cast<const bf16x8*>(&Ah[m * AST + quad * 8]);
            a_l[fi] = *reinterpret_cast<const bf16x8*>(&Al[m * AST + quad * 8]);
            const int n = wn * 64 + fi * 16 + lanelo;
            b_h[fi] = *reinterpret_cast<const bf16x8*>(&Bh[n * AST + quad * 8]);
            b_l[fi] = *reinterpret_cast<const bf16x8*>(&Bl[n * AST + quad * 8]);
        }
        #pragma unroll
        for (int fi = 0; fi < 4; ++fi)
            #pragma unroll
            for (int fj = 0; fj < 4; ++fj) {
                acc[fi][fj] = __builtin_amdgcn_mfma_f32_16x16x32_bf16(
                    a_h[fi], b_h[fj], acc[fi][fj], 0, 0, 0);
                acc[fi][fj] = __builtin_amdgcn_mfma_f32_16x16x32_bf16(
                    a_h[fi], b_l[fj], acc[fi][fj], 0, 0, 0);
                acc[fi][fj] = __builtin_amdgcn_mfma_f32_16x16x32_bf16(
                    a_l[fi], b_h[fj], acc[fi][fj], 0, 0, 0);
            }
        __syncthreads();
    }
    const float* hb_row = hb + batch * H_;
    float hbv[4], vv[4];
    #pragma unroll
    for (int fj = 0; fj < 4; ++fj) {
        const int c = col0 + wn * 64 + fj * 16 + lanelo;
        hbv[fj] = hb_row[c];
        vv[fj]  = v[c];
    }
    float* red = reinterpret_cast<float*>(Ah);
    #pragma unroll
    for (int fi = 0; fi < 4; ++fi)
        #pragma unroll
        for (int r = 0; r < 4; ++r) {
            float rs = 0.f;
            #pragma unroll
            for (int fj = 0; fj < 4; ++fj)
                rs = fmaf(tanhf(acc[fi][fj][r] + hbv[fj]), vv[fj], rs);
            rs += __shfl_xor(rs, 1, 64);
            rs += __shfl_xor(rs, 2, 64);
            rs += __shfl_xor(rs, 4, 64);
            rs += __shfl_xor(rs, 8, 64);
            if (lanelo == 0) {
                const int row = wm * 64 + fi * 16 + quad * 4 + r;
                red[row * 2 + wn] = rs;
            }
        }
    __syncthreads();
    if (tid < 128)
        partial[(size_t)nt * M_ + row0 + tid] = red[tid * 2] + red[tid * 2 + 1];
}

// ---------------------------------------------------------------------------
// Kernel 3: per-batch softmax over S=1024 (sum of 4 partials)
// ---------------------------------------------------------------------------
__global__ __launch_bounds__(256) void softmax_kernel(
    const float* __restrict__ partial, float* __restrict__ out)
{
    const int b = blockIdx.x;
    const int tid = threadIdx.x;
    float val[4];
    float lmax = -3.0e38f;
    #pragma unroll
    for (int q = 0; q < 4; ++q) {
        const int idx = b * S_ + tid + 256 * q;
        float sum = partial[idx] + partial[M_ + idx] + partial[2 * M_ + idx] +
                    partial[3 * M_ + idx];
        val[q] = sum;
        lmax = fmaxf(lmax, sum);
    }
    #pragma unroll
    for (int off = 32; off > 0; off >>= 1)
        lmax = fmaxf(lmax, __shfl_down(lmax, off, 64));
    __shared__ float wmax[4];
    if ((tid & 63) == 0) wmax[tid >> 6] = lmax;
    __syncthreads();
    const float gmax = fmaxf(fmaxf(wmax[0], wmax[1]), fmaxf(wmax[2], wmax[3]));
    float lsum = 0.0f;
    #pragma unroll
    for (int q = 0; q < 4; ++q) {
        val[q] = expf(val[q] - gmax);
        lsum += val[q];
    }
    #pragma unroll
    for (int off = 32; off > 0; off >>= 1)
        lsum += __shfl_down(lsum, off, 64);
    __shared__ float wsum[4];
    if ((tid & 63) == 0) wsum[tid >> 6] = lsum;
    __syncthreads();
    const float inv = 1.0f / (wsum[0] + wsum[1] + wsum[2] + wsum[3]);
    #pragma unroll
    for (int q = 0; q < 4; ++q)
        out[b * S_ + tid + 256 * q] = val[q] * inv;
}

// ---------------------------------------------------------------------------
extern "C" void kernel_launch(void* const* d_in, const int* in_sizes, int n_in,
                              void* d_out, int out_size, void* d_ws, size_t ws_size,
                              hipStream_t stream) {
    const float* hidden = (const float*)d_in[0];
    const float* EO     = (const float*)d_in[1];
    const float* W      = (const float*)d_in[2];
    const float* bias   = (const float*)d_in[3];
    const float* v      = (const float*)d_in[4];
    float* out          = (float*)d_out;

    float* hb      = (float*)d_ws;                       // 16384 floats
    float* partial = hb + B_ * H_;                       // 131072 floats
    unsigned short* Wth = (unsigned short*)(partial + 4 * M_);
    unsigned short* Wtl = Wth + (size_t)H_ * K_;
    unsigned short* EOh = Wtl + (size_t)H_ * K_;
    unsigned short* EOl = EOh + (size_t)M_ * K_;

    const size_t need_small = (size_t)(B_ * H_ + 4 * M_) * sizeof(float)
                            + (size_t)H_ * K_ * 2 * sizeof(unsigned short);
    const size_t need_full  = need_small
                            + (size_t)M_ * K_ * 2 * sizeof(unsigned short);

    const float* We = W + (size_t)H_ * H_;               // rows [H, 3H)

    hproj_kernel<<<dim3(8, B_), 256, 0, stream>>>(hidden, W, bias, hb);
    conv_we_kernel<<<dim3(K_ / 32, H_ / 32), 256, 0, stream>>>(We, Wth, Wtl);
    if (ws_size >= need_full) {
        split_eo_kernel<<<(size_t)M_ * K_ / (256 * 8), 256, 0, stream>>>(EO, EOh, EOl);
        gemm_mfma_pre<<<dim3(4, M_ / 128), 256, 0, stream>>>(EOh, EOl, Wth, Wtl, hb, v, partial);
    } else {
        fused_attn_gemm_mfma<<<dim3(4, M_ / 128), 256, 0, stream>>>(EO, Wth, Wtl, hb, v, partial);
    }
    softmax_kernel<<<B_, 256, 0, stream>>>(partial, out);
}

// Round 4
// 347.004 us; speedup vs baseline: 1.0219x; 1.0219x over previous
//
#include <hip/hip_runtime.h>
#include <math.h>

#define B_ 32
#define S_ 1024
#define H_ 512
#define K_ 1024                 // 2*H
#define M_ (B_ * S_)            // 32768

typedef __attribute__((ext_vector_type(8))) short bf16x8;
typedef __attribute__((ext_vector_type(4))) float f32x4;

// RNE split: f = hi + lo with hi,lo bf16; dropped cross-term ~2^-18 relative
__device__ __forceinline__ void split_bf16(float f, unsigned short& hi, unsigned short& lo) {
    unsigned u = __float_as_uint(f);
    unsigned rh = (u + 0x7fffu + ((u >> 16) & 1u)) >> 16;
    hi = (unsigned short)rh;
    float fh = __uint_as_float(rh << 16);
    float r = f - fh;                      // exact (Veltkamp-style split)
    unsigned ur = __float_as_uint(r);
    unsigned rl = (ur + 0x7fffu + ((ur >> 16) & 1u)) >> 16;
    lo = (unsigned short)rl;
}

// async 16B global -> LDS (lane i lands at lds_base + i*16; lds_base wave-uniform)
__device__ __forceinline__ void async_copy16(const void* g, void* l) {
    __builtin_amdgcn_global_load_lds(
        (const __attribute__((address_space(1))) void*)g,
        (__attribute__((address_space(3))) void*)l, 16, 0, 0);
}

// ---------------------------------------------------------------------------
// Kernel 0: split EO (M*K fp32) -> EOh/EOl (bf16). Memory-bound, ~268 MB.
// 4 independent dense float4 chunks per thread for MLP.
// ---------------------------------------------------------------------------
__global__ __launch_bounds__(256) void split_eo_kernel(
    const float* __restrict__ EO, unsigned short* __restrict__ EOh,
    unsigned short* __restrict__ EOl)
{
    const size_t base = (size_t)blockIdx.x * 4096 + (size_t)threadIdx.x * 4;
    float4 a[4];
    #pragma unroll
    for (int j = 0; j < 4; ++j)
        a[j] = *reinterpret_cast<const float4*>(EO + base + j * 1024);
    #pragma unroll
    for (int j = 0; j < 4; ++j) {
        union { unsigned short us[4]; uint2 u2; } h, l;
        split_bf16(a[j].x, h.us[0], l.us[0]);
        split_bf16(a[j].y, h.us[1], l.us[1]);
        split_bf16(a[j].z, h.us[2], l.us[2]);
        split_bf16(a[j].w, h.us[3], l.us[3]);
        *reinterpret_cast<uint2*>(EOh + base + j * 1024) = h.u2;
        *reinterpret_cast<uint2*>(EOl + base + j * 1024) = l.u2;
    }
}

// ---------------------------------------------------------------------------
// Kernel 1: hb[b][h] = sum_k hidden[b][k]*W[k][h] + bias[h]
// ---------------------------------------------------------------------------
__global__ __launch_bounds__(256) void hproj_kernel(
    const float* __restrict__ hidden, const float* __restrict__ W,
    const float* __restrict__ bias, float* __restrict__ hb)
{
    const int tid = threadIdx.x;
    const int h0  = blockIdx.x * 64;
    const int b   = blockIdx.y;
    const int h   = h0 + (tid & 63);
    const int ks  = tid >> 6;              // 4 k-slices of 128
    const float* hrow = hidden + b * H_;
    float acc = 0.f;
    #pragma unroll 8
    for (int k = ks * 128; k < ks * 128 + 128; ++k)
        acc = fmaf(hrow[k], W[(size_t)k * H_ + h], acc);
    __shared__ float red[4][64];
    red[ks][tid & 63] = acc;
    __syncthreads();
    if (tid < 64)
        hb[b * H_ + h0 + tid] = red[0][tid] + red[1][tid] + red[2][tid] + red[3][tid]
                              + bias[h0 + tid];
}

// ---------------------------------------------------------------------------
// Kernel 1b: transpose + bf16-split We (K x 512) -> Wth/Wtl (512 x K)
// ---------------------------------------------------------------------------
__global__ __launch_bounds__(256) void conv_we_kernel(
    const float* __restrict__ We, unsigned short* __restrict__ Wh,
    unsigned short* __restrict__ Wl)
{
    __shared__ float t[32][33];
    const int tx = threadIdx.x & 31, ty = threadIdx.x >> 5;   // ty 0..7
    const int k0 = blockIdx.x * 32, n0 = blockIdx.y * 32;
    #pragma unroll
    for (int j = 0; j < 4; ++j) {
        const int k = ty + 8 * j;
        t[k][tx] = We[(size_t)(k0 + k) * H_ + n0 + tx];
    }
    __syncthreads();
    #pragma unroll
    for (int j = 0; j < 4; ++j) {
        const int n = ty + 8 * j;
        unsigned short hi, lo;
        split_bf16(t[tx][n], hi, lo);
        Wh[(size_t)(n0 + n) * K_ + k0 + tx] = hi;
        Wl[(size_t)(n0 + n) * K_ + k0 + tx] = lo;
    }
}

// ---------------------------------------------------------------------------
// Kernel 2: MFMA GEMM from pre-split bf16, double-buffered global_load_lds.
//   Block 128x128, BK=32, 4 waves of 64x64, 16x16x32 bf16 MFMA x3 (split).
//   XOR quarter swizzle (conflict-free, verified r3: SQ_LDS_BANK_CONFLICT=0).
//   Prefetch for iter i+1 issued right AFTER barrier_i -> the vmcnt(0) drain
//   at barrier_{i+1} waits on loads that have been in flight one full body.
// ---------------------------------------------------------------------------
__global__ __launch_bounds__(256, 2) void gemm_mfma_pre(
    const unsigned short* __restrict__ EOh, const unsigned short* __restrict__ EOl,
    const unsigned short* __restrict__ Bth, const unsigned short* __restrict__ Btl,
    const float* __restrict__ hb, const float* __restrict__ v,
    float* __restrict__ partial)
{
    __shared__ unsigned short lds[2][4][4096];   // [buf][Ah|Al|Bh|Bl][128x32]

    const int tid  = threadIdx.x;
    const int nt   = blockIdx.x;              // 0..3 fastest: A L2/L3 sharing
    const int mt   = blockIdx.y;              // 0..255
    const int row0 = mt * 128;
    const int col0 = nt * 128;
    const int batch = row0 >> 10;

    const int lane   = tid & 63;
    const int wave   = tid >> 6;
    const int wm     = wave >> 1, wn = wave & 1;
    const int lanelo = lane & 15, quad = lane >> 4;

    // staging geometry: issue = 16 rows x 64B = 1KB; wave w does issues 2w,2w+1
    const int rl = lane >> 2;                 // row within issue (0..15)
    const int qs = lane & 3;                  // LDS quarter slot (16B units)

    size_t ga[2], gb[2];
    int ldsoff[2];
    #pragma unroll
    for (int j = 0; j < 2; ++j) {
        const int iss = wave * 2 + j;
        const int r   = iss * 16 + rl;        // tile row 0..127
        const int qg  = qs ^ ((r >> 1) & 3);  // swizzled global quarter
        ga[j] = (size_t)(row0 + r) * K_ + qg * 8;
        gb[j] = (size_t)(col0 + r) * K_ + qg * 8;
        ldsoff[j] = iss * 512;                // shorts (1KB per issue)
    }

    f32x4 acc[4][4];
    #pragma unroll
    for (int i = 0; i < 4; ++i)
        #pragma unroll
        for (int j = 0; j < 4; ++j)
            acc[i][j] = (f32x4){0.f, 0.f, 0.f, 0.f};

    // prologue: stage k=0 into buf 0
    #pragma unroll
    for (int j = 0; j < 2; ++j) {
        async_copy16(EOh + ga[j], &lds[0][0][ldsoff[j]]);
        async_copy16(EOl + ga[j], &lds[0][1][ldsoff[j]]);
        async_copy16(Bth + gb[j], &lds[0][2][ldsoff[j]]);
        async_copy16(Btl + gb[j], &lds[0][3][ldsoff[j]]);
    }

    for (int i = 0; i < 32; ++i) {
        __syncthreads();                      // drains prefetch issued last iter
        const int cur = i & 1;
        if (i < 31) {                         // prefetch k-tile i+1 into other buf
            const int nxt = (i + 1) & 1;
            const int k0 = 32 * (i + 1);
            #pragma unroll
            for (int j = 0; j < 2; ++j) {
                async_copy16(EOh + ga[j] + k0, &lds[nxt][0][ldsoff[j]]);
                async_copy16(EOl + ga[j] + k0, &lds[nxt][1][ldsoff[j]]);
                async_copy16(Bth + gb[j] + k0, &lds[nxt][2][ldsoff[j]]);
                async_copy16(Btl + gb[j] + k0, &lds[nxt][3][ldsoff[j]]);
            }
        }

        bf16x8 a_h[4], a_l[4], b_h[4], b_l[4];
        #pragma unroll
        for (int fi = 0; fi < 4; ++fi) {
            const int m  = wm * 64 + fi * 16 + lanelo;
            const int sa = quad ^ ((m >> 1) & 3);
            a_h[fi] = *reinterpret_cast<const bf16x8*>(&lds[cur][0][m * 32 + sa * 8]);
            a_l[fi] = *reinterpret_cast<const bf16x8*>(&lds[cur][1][m * 32 + sa * 8]);
            const int n  = wn * 64 + fi * 16 + lanelo;
            const int sb = quad ^ ((n >> 1) & 3);
            b_h[fi] = *reinterpret_cast<const bf16x8*>(&lds[cur][2][n * 32 + sb * 8]);
            b_l[fi] = *reinterpret_cast<const bf16x8*>(&lds[cur][3][n * 32 + sb * 8]);
        }
        #pragma unroll
        for (int fi = 0; fi < 4; ++fi)
            #pragma unroll
            for (int fj = 0; fj < 4; ++fj) {
                acc[fi][fj] = __builtin_amdgcn_mfma_f32_16x16x32_bf16(
                    a_h[fi], b_h[fj], acc[fi][fj], 0, 0, 0);
                acc[fi][fj] = __builtin_amdgcn_mfma_f32_16x16x32_bf16(
                    a_h[fi], b_l[fj], acc[fi][fj], 0, 0, 0);
                acc[fi][fj] = __builtin_amdgcn_mfma_f32_16x16x32_bf16(
                    a_l[fi], b_h[fj], acc[fi][fj], 0, 0, 0);
            }
    }

    // ---- epilogue: tanh(acc + hb)*v, reduce over this block's 128 cols ----
    // Last iter (i=31) read buf 1; `red` reuses buf 0 -> no cross-wave hazard.
    const float* hb_row = hb + batch * H_;
    float hbv[4], vv[4];
    #pragma unroll
    for (int fj = 0; fj < 4; ++fj) {
        const int c = col0 + wn * 64 + fj * 16 + lanelo;
        hbv[fj] = hb_row[c];
        vv[fj]  = v[c];
    }
    float* red = reinterpret_cast<float*>(&lds[0][0][0]);   // 256 floats
    #pragma unroll
    for (int fi = 0; fi < 4; ++fi)
        #pragma unroll
        for (int r = 0; r < 4; ++r) {
            float rs = 0.f;
            #pragma unroll
            for (int fj = 0; fj < 4; ++fj)
                rs = fmaf(tanhf(acc[fi][fj][r] + hbv[fj]), vv[fj], rs);
            rs += __shfl_xor(rs, 1, 64);
            rs += __shfl_xor(rs, 2, 64);
            rs += __shfl_xor(rs, 4, 64);
            rs += __shfl_xor(rs, 8, 64);
            if (lanelo == 0) {
                const int row = wm * 64 + fi * 16 + quad * 4 + r;
                red[row * 2 + wn] = rs;
            }
        }
    __syncthreads();
    if (tid < 128)
        partial[(size_t)nt * M_ + row0 + tid] = red[tid * 2] + red[tid * 2 + 1];
}

// ---------------------------------------------------------------------------
// Fallback: MFMA GEMM with in-kernel A split (if ws too small)
// ---------------------------------------------------------------------------
#define AST 40
__global__ __launch_bounds__(256, 3) void fused_attn_gemm_mfma(
    const float* __restrict__ EO, const unsigned short* __restrict__ Bth,
    const unsigned short* __restrict__ Btl, const float* __restrict__ hb,
    const float* __restrict__ v, float* __restrict__ partial)
{
    __shared__ unsigned short Ah[128 * AST];
    __shared__ unsigned short Al[128 * AST];
    __shared__ unsigned short Bh[128 * AST];
    __shared__ unsigned short Bl[128 * AST];
    const int tid  = threadIdx.x;
    const int nt   = blockIdx.x;
    const int mt   = blockIdx.y;
    const int row0 = mt * 128, col0 = nt * 128;
    const int batch = row0 >> 10;
    const int lane = tid & 63, wave = tid >> 6;
    const int wm = wave >> 1, wn = wave & 1;
    const int lanelo = lane & 15, quad = lane >> 4;
    f32x4 acc[4][4];
    #pragma unroll
    for (int i = 0; i < 4; ++i)
        #pragma unroll
        for (int j = 0; j < 4; ++j) acc[i][j] = (f32x4){0.f, 0.f, 0.f, 0.f};
    for (int k0 = 0; k0 < K_; k0 += 32) {
        #pragma unroll
        for (int q = 0; q < 4; ++q) {
            const int f = tid + 256 * q;
            const int m = f >> 3, c = f & 7;
            const float4 av = *reinterpret_cast<const float4*>(
                EO + (size_t)(row0 + m) * K_ + k0 + c * 4);
            union { unsigned short us[4]; uint2 u2; } ph, pl;
            split_bf16(av.x, ph.us[0], pl.us[0]);
            split_bf16(av.y, ph.us[1], pl.us[1]);
            split_bf16(av.z, ph.us[2], pl.us[2]);
            split_bf16(av.w, ph.us[3], pl.us[3]);
            *reinterpret_cast<uint2*>(&Ah[m * AST + c * 4]) = ph.u2;
            *reinterpret_cast<uint2*>(&Al[m * AST + c * 4]) = pl.u2;
        }
        #pragma unroll
        for (int q = 0; q < 2; ++q) {
            const int s = tid + 256 * q;
            const int n = s >> 2, qq = s & 3;
            const size_t g = (size_t)(col0 + n) * K_ + k0 + qq * 8;
            *reinterpret_cast<uint4*>(&Bh[n * AST + qq * 8]) =
                *reinterpret_cast<const uint4*>(Bth + g);
            *reinterpret_cast<uint4*>(&Bl[n * AST + qq * 8]) =
                *reinterpret_cast<const uint4*>(Btl + g);
        }
        __syncthreads();
        bf16x8 a_h[4], a_l[4], b_h[4], b_l[4];
        #pragma unroll
        for (int fi = 0; fi < 4; ++fi) {
            const int m = wm * 64 + fi * 16 + lanelo;
            a_h[fi] = *reinterpret_cast<const bf16x8*>(&Ah[m * AST + quad * 8]);
            a_l[fi] = *reinterpret_cast<const bf16x8*>(&Al[m * AST + quad * 8]);
            const int n = wn * 64 + fi * 16 + lanelo;
            b_h[fi] = *reinterpret_cast<const bf16x8*>(&Bh[n * AST + quad * 8]);
            b_l[fi] = *reinterpret_cast<const bf16x8*>(&Bl[n * AST + quad * 8]);
        }
        #pragma unroll
        for (int fi = 0; fi < 4; ++fi)
            #pragma unroll
            for (int fj = 0; fj < 4; ++fj) {
                acc[fi][fj] = __builtin_amdgcn_mfma_f32_16x16x32_bf16(
                    a_h[fi], b_h[fj], acc[fi][fj], 0, 0, 0);
                acc[fi][fj] = __builtin_amdgcn_mfma_f32_16x16x32_bf16(
                    a_h[fi], b_l[fj], acc[fi][fj], 0, 0, 0);
                acc[fi][fj] = __builtin_amdgcn_mfma_f32_16x16x32_bf16(
                    a_l[fi], b_h[fj], acc[fi][fj], 0, 0, 0);
            }
        __syncthreads();
    }
    const float* hb_row = hb + batch * H_;
    float hbv[4], vv[4];
    #pragma unroll
    for (int fj = 0; fj < 4; ++fj) {
        const int c = col0 + wn * 64 + fj * 16 + lanelo;
        hbv[fj] = hb_row[c];
        vv[fj]  = v[c];
    }
    float* red = reinterpret_cast<float*>(Ah);
    #pragma unroll
    for (int fi = 0; fi < 4; ++fi)
        #pragma unroll
        for (int r = 0; r < 4; ++r) {
            float rs = 0.f;
            #pragma unroll
            for (int fj = 0; fj < 4; ++fj)
                rs = fmaf(tanhf(acc[fi][fj][r] + hbv[fj]), vv[fj], rs);
            rs += __shfl_xor(rs, 1, 64);
            rs += __shfl_xor(rs, 2, 64);
            rs += __shfl_xor(rs, 4, 64);
            rs += __shfl_xor(rs, 8, 64);
            if (lanelo == 0) {
                const int row = wm * 64 + fi * 16 + quad * 4 + r;
                red[row * 2 + wn] = rs;
            }
        }
    __syncthreads();
    if (tid < 128)
        partial[(size_t)nt * M_ + row0 + tid] = red[tid * 2] + red[tid * 2 + 1];
}

// ---------------------------------------------------------------------------
// Kernel 3: per-batch softmax over S=1024 (sum of 4 partials)
// ---------------------------------------------------------------------------
__global__ __launch_bounds__(256) void softmax_kernel(
    const float* __restrict__ partial, float* __restrict__ out)
{
    const int b = blockIdx.x;
    const int tid = threadIdx.x;
    float val[4];
    float lmax = -3.0e38f;
    #pragma unroll
    for (int q = 0; q < 4; ++q) {
        const int idx = b * S_ + tid + 256 * q;
        float sum = partial[idx] + partial[M_ + idx] + partial[2 * M_ + idx] +
                    partial[3 * M_ + idx];
        val[q] = sum;
        lmax = fmaxf(lmax, sum);
    }
    #pragma unroll
    for (int off = 32; off > 0; off >>= 1)
        lmax = fmaxf(lmax, __shfl_down(lmax, off, 64));
    __shared__ float wmax[4];
    if ((tid & 63) == 0) wmax[tid >> 6] = lmax;
    __syncthreads();
    const float gmax = fmaxf(fmaxf(wmax[0], wmax[1]), fmaxf(wmax[2], wmax[3]));
    float lsum = 0.0f;
    #pragma unroll
    for (int q = 0; q < 4; ++q) {
        val[q] = expf(val[q] - gmax);
        lsum += val[q];
    }
    #pragma unroll
    for (int off = 32; off > 0; off >>= 1)
        lsum += __shfl_down(lsum, off, 64);
    __shared__ float wsum[4];
    if ((tid & 63) == 0) wsum[tid >> 6] = lsum;
    __syncthreads();
    const float inv = 1.0f / (wsum[0] + wsum[1] + wsum[2] + wsum[3]);
    #pragma unroll
    for (int q = 0; q < 4; ++q)
        out[b * S_ + tid + 256 * q] = val[q] * inv;
}

// ---------------------------------------------------------------------------
extern "C" void kernel_launch(void* const* d_in, const int* in_sizes, int n_in,
                              void* d_out, int out_size, void* d_ws, size_t ws_size,
                              hipStream_t stream) {
    const float* hidden = (const float*)d_in[0];
    const float* EO     = (const float*)d_in[1];
    const float* W      = (const float*)d_in[2];
    const float* bias   = (const float*)d_in[3];
    const float* v      = (const float*)d_in[4];
    float* out          = (float*)d_out;

    float* hb      = (float*)d_ws;                       // 16384 floats
    float* partial = hb + B_ * H_;                       // 131072 floats
    unsigned short* Wth = (unsigned short*)(partial + 4 * M_);
    unsigned short* Wtl = Wth + (size_t)H_ * K_;
    unsigned short* EOh = Wtl + (size_t)H_ * K_;
    unsigned short* EOl = EOh + (size_t)M_ * K_;

    const size_t need_small = (size_t)(B_ * H_ + 4 * M_) * sizeof(float)
                            + (size_t)H_ * K_ * 2 * sizeof(unsigned short);
    const size_t need_full  = need_small
                            + (size_t)M_ * K_ * 2 * sizeof(unsigned short);

    const float* We = W + (size_t)H_ * H_;               // rows [H, 3H)

    hproj_kernel<<<dim3(8, B_), 256, 0, stream>>>(hidden, W, bias, hb);
    conv_we_kernel<<<dim3(K_ / 32, H_ / 32), 256, 0, stream>>>(We, Wth, Wtl);
    if (ws_size >= need_full) {
        split_eo_kernel<<<(size_t)M_ * K_ / 4096, 256, 0, stream>>>(EO, EOh, EOl);
        gemm_mfma_pre<<<dim3(4, M_ / 128), 256, 0, stream>>>(EOh, EOl, Wth, Wtl, hb, v, partial);
    } else {
        fused_attn_gemm_mfma<<<dim3(4, M_ / 128), 256, 0, stream>>>(EO, Wth, Wtl, hb, v, partial);
    }
    softmax_kernel<<<B_, 256, 0, stream>>>(partial, out);
}

// Round 5
// 317.043 us; speedup vs baseline: 1.1184x; 1.0945x over previous
//
#include <hip/hip_runtime.h>
#include <math.h>

#define B_ 32
#define S_ 1024
#define H_ 512
#define K_ 1024                 // 2*H
#define M_ (B_ * S_)            // 32768

typedef __attribute__((ext_vector_type(8))) short bf16x8;
typedef __attribute__((ext_vector_type(4))) float f32x4;

// RNE split: f = hi + lo with hi,lo bf16; dropped cross-term ~2^-18 relative
__device__ __forceinline__ void split_bf16(float f, unsigned short& hi, unsigned short& lo) {
    unsigned u = __float_as_uint(f);
    unsigned rh = (u + 0x7fffu + ((u >> 16) & 1u)) >> 16;
    hi = (unsigned short)rh;
    float fh = __uint_as_float(rh << 16);
    float r = f - fh;                      // exact (Veltkamp-style split)
    unsigned ur = __float_as_uint(r);
    unsigned rl = (ur + 0x7fffu + ((ur >> 16) & 1u)) >> 16;
    lo = (unsigned short)rl;
}

// split 8 floats -> two 16B LDS stores (ds_write_b128)
__device__ __forceinline__ void split8_store(const float4& x, const float4& y,
                                             unsigned short* hiP, unsigned short* loP) {
    union { unsigned short us[8]; uint4 u; } h, l;
    split_bf16(x.x, h.us[0], l.us[0]);
    split_bf16(x.y, h.us[1], l.us[1]);
    split_bf16(x.z, h.us[2], l.us[2]);
    split_bf16(x.w, h.us[3], l.us[3]);
    split_bf16(y.x, h.us[4], l.us[4]);
    split_bf16(y.y, h.us[5], l.us[5]);
    split_bf16(y.z, h.us[6], l.us[6]);
    split_bf16(y.w, h.us[7], l.us[7]);
    *reinterpret_cast<uint4*>(hiP) = h.u;
    *reinterpret_cast<uint4*>(loP) = l.u;
}

// async 16B global -> LDS (lane i lands at lds_base + i*16; lds_base wave-uniform)
__device__ __forceinline__ void async_copy16(const void* g, void* l) {
    __builtin_amdgcn_global_load_lds(
        (const __attribute__((address_space(1))) void*)g,
        (__attribute__((address_space(3))) void*)l, 16, 0, 0);
}

// ---------------------------------------------------------------------------
// Kernel 1: merged prep.
//   blocks [0,256):  hb[b][h] = sum_k hidden[b][k]*W[k][h] + bias[h]
//   blocks [256,768): transpose + bf16-split We (K x 512) -> Wth/Wtl (512 x K)
// ---------------------------------------------------------------------------
__global__ __launch_bounds__(256) void prep_kernel(
    const float* __restrict__ hidden, const float* __restrict__ W,
    const float* __restrict__ bias, float* __restrict__ hb,
    unsigned short* __restrict__ Wh, unsigned short* __restrict__ Wl)
{
    __shared__ float red[4][64];
    __shared__ float t[32][33];
    const int bx = blockIdx.x;
    if (bx < 256) {
        const int tid = threadIdx.x;
        const int h0  = (bx & 7) * 64;
        const int b   = bx >> 3;
        const int h   = h0 + (tid & 63);
        const int ks  = tid >> 6;              // 4 k-slices of 128
        const float* hrow = hidden + b * H_;
        float acc = 0.f;
        #pragma unroll 8
        for (int k = ks * 128; k < ks * 128 + 128; ++k)
            acc = fmaf(hrow[k], W[(size_t)k * H_ + h], acc);
        red[ks][tid & 63] = acc;
        __syncthreads();
        if (tid < 64)
            hb[b * H_ + h0 + tid] = red[0][tid] + red[1][tid] + red[2][tid]
                                  + red[3][tid] + bias[h0 + tid];
    } else {
        const float* We = W + (size_t)H_ * H_;   // rows [H, 3H)
        const int cx = bx - 256;                  // 0..511
        const int k0 = (cx & 31) * 32, n0 = (cx >> 5) * 32;
        const int tx = threadIdx.x & 31, ty = threadIdx.x >> 5;   // ty 0..7
        #pragma unroll
        for (int j = 0; j < 4; ++j) {
            const int k = ty + 8 * j;
            t[k][tx] = We[(size_t)(k0 + k) * H_ + n0 + tx];
        }
        __syncthreads();
        #pragma unroll
        for (int j = 0; j < 4; ++j) {
            const int n = ty + 8 * j;
            unsigned short hi, lo;
            split_bf16(t[tx][n], hi, lo);
            Wh[(size_t)(n0 + n) * K_ + k0 + tx] = hi;
            Wl[(size_t)(n0 + n) * K_ + k0 + tx] = lo;
        }
    }
}

// ---------------------------------------------------------------------------
// Kernel 2: MFMA GEMM, in-loop A split, double-buffered.
//   A: fp32 global -> regs (issued after barrier, consumed after MFMA block)
//      -> split -> ds_write_b128 into next buffer.  B: pre-split bf16 via
//      global_load_lds DMA.  XOR quarter swizzle on both (conflict-free, r3).
//   Block 128x128, BK=32, 4 waves 2x2 of 64x64, 16x16x32 bf16 MFMA x3.
// ---------------------------------------------------------------------------
__global__ __launch_bounds__(256, 2) void gemm_fused(
    const float* __restrict__ EO,             // (M, K) fp32
    const unsigned short* __restrict__ Bth,   // (512, K) bf16 hi
    const unsigned short* __restrict__ Btl,   // (512, K) bf16 lo
    const float* __restrict__ hb, const float* __restrict__ v,
    float* __restrict__ partial)              // (4, M)
{
    __shared__ unsigned short ldsA[2][2][4096];   // [buf][hi|lo][128*32]
    __shared__ unsigned short ldsB[2][2][4096];

    const int tid  = threadIdx.x;
    const int nt   = blockIdx.x;              // 0..3 fastest: A L2/L3 sharing
    const int mt   = blockIdx.y;              // 0..255
    const int row0 = mt * 128;
    const int col0 = nt * 128;
    const int batch = row0 >> 10;

    const int lane   = tid & 63;
    const int wave   = tid >> 6;
    const int wm     = wave >> 1, wn = wave & 1;
    const int lanelo = lane & 15, quad = lane >> 4;

    // ---- A staging geometry: seg = tid + 256*s; m = seg>>2; sg = seg&3 ----
    size_t gaA[2];
    int offA[2];
    #pragma unroll
    for (int s = 0; s < 2; ++s) {
        const int seg = tid + 256 * s;
        const int m = seg >> 2, sg = seg & 3;
        gaA[s] = (size_t)(row0 + m) * K_ + sg * 8;
        offA[s] = m * 32 + (sg ^ ((m >> 1) & 3)) * 8;
    }
    // ---- B staging geometry (DMA): issue = 16 rows x 64B; wave w: 2w,2w+1 ----
    size_t gb[2];
    int offB[2];
    #pragma unroll
    for (int j = 0; j < 2; ++j) {
        const int iss = wave * 2 + j;
        const int r   = iss * 16 + (lane >> 2);
        const int qg  = (lane & 3) ^ ((r >> 1) & 3);
        gb[j] = (size_t)(col0 + r) * K_ + qg * 8;
        offB[j] = iss * 512;                  // shorts
    }

    f32x4 acc[4][4];
    #pragma unroll
    for (int i = 0; i < 4; ++i)
        #pragma unroll
        for (int j = 0; j < 4; ++j)
            acc[i][j] = (f32x4){0.f, 0.f, 0.f, 0.f};

    // ---- prologue: stage tile 0 ----
    float4 a0[2], a1[2];
    #pragma unroll
    for (int s = 0; s < 2; ++s) {
        a0[s] = *reinterpret_cast<const float4*>(EO + gaA[s]);
        a1[s] = *reinterpret_cast<const float4*>(EO + gaA[s] + 4);
    }
    #pragma unroll
    for (int j = 0; j < 2; ++j) {
        async_copy16(Bth + gb[j], &ldsB[0][0][offB[j]]);
        async_copy16(Btl + gb[j], &ldsB[0][1][offB[j]]);
    }
    #pragma unroll
    for (int s = 0; s < 2; ++s)
        split8_store(a0[s], a1[s], &ldsA[0][0][offA[s]], &ldsA[0][1][offA[s]]);

    for (int i = 0; i < 32; ++i) {
        __syncthreads();                      // buf[cur] ready (vmcnt+lgkm drain)
        const int cur = i & 1, nxt = cur ^ 1;
        const int k0n = 32 * (i + 1);
        if (i < 31) {
            // issue next A register loads first (so awaiting them later
            // leaves B DMA still in flight), then B DMA.
            #pragma unroll
            for (int s = 0; s < 2; ++s) {
                a0[s] = *reinterpret_cast<const float4*>(EO + gaA[s] + k0n);
                a1[s] = *reinterpret_cast<const float4*>(EO + gaA[s] + k0n + 4);
            }
            #pragma unroll
            for (int j = 0; j < 2; ++j) {
                async_copy16(Bth + gb[j] + k0n, &ldsB[nxt][0][offB[j]]);
                async_copy16(Btl + gb[j] + k0n, &ldsB[nxt][1][offB[j]]);
            }
        }

        bf16x8 a_h[4], a_l[4], b_h[4], b_l[4];
        #pragma unroll
        for (int fi = 0; fi < 4; ++fi) {
            const int m  = wm * 64 + fi * 16 + lanelo;
            const int sa = quad ^ ((m >> 1) & 3);
            a_h[fi] = *reinterpret_cast<const bf16x8*>(&ldsA[cur][0][m * 32 + sa * 8]);
            a_l[fi] = *reinterpret_cast<const bf16x8*>(&ldsA[cur][1][m * 32 + sa * 8]);
            const int n  = wn * 64 + fi * 16 + lanelo;
            const int sb = quad ^ ((n >> 1) & 3);
            b_h[fi] = *reinterpret_cast<const bf16x8*>(&ldsB[cur][0][n * 32 + sb * 8]);
            b_l[fi] = *reinterpret_cast<const bf16x8*>(&ldsB[cur][1][n * 32 + sb * 8]);
        }
        #pragma unroll
        for (int fi = 0; fi < 4; ++fi)
            #pragma unroll
            for (int fj = 0; fj < 4; ++fj) {
                acc[fi][fj] = __builtin_amdgcn_mfma_f32_16x16x32_bf16(
                    a_h[fi], b_h[fj], acc[fi][fj], 0, 0, 0);
                acc[fi][fj] = __builtin_amdgcn_mfma_f32_16x16x32_bf16(
                    a_h[fi], b_l[fj], acc[fi][fj], 0, 0, 0);
                acc[fi][fj] = __builtin_amdgcn_mfma_f32_16x16x32_bf16(
                    a_l[fi], b_h[fj], acc[fi][fj], 0, 0, 0);
            }

        if (i < 31) {                         // split+stage A(i+1) after MFMAs
            #pragma unroll
            for (int s = 0; s < 2; ++s)
                split8_store(a0[s], a1[s],
                             &ldsA[nxt][0][offA[s]], &ldsA[nxt][1][offA[s]]);
        }
    }

    // ---- epilogue: tanh(acc + hb)*v, reduce over this block's 128 cols ----
    // Last iter read buf 1; red reuses ldsA[0] (disjoint) -> no hazard.
    const float* hb_row = hb + batch * H_;
    float hbv[4], vv[4];
    #pragma unroll
    for (int fj = 0; fj < 4; ++fj) {
        const int c = col0 + wn * 64 + fj * 16 + lanelo;
        hbv[fj] = hb_row[c];
        vv[fj]  = v[c];
    }
    float* red = reinterpret_cast<float*>(&ldsA[0][0][0]);   // 256 floats
    #pragma unroll
    for (int fi = 0; fi < 4; ++fi)
        #pragma unroll
        for (int r = 0; r < 4; ++r) {
            float rs = 0.f;
            #pragma unroll
            for (int fj = 0; fj < 4; ++fj)
                rs = fmaf(tanhf(acc[fi][fj][r] + hbv[fj]), vv[fj], rs);
            rs += __shfl_xor(rs, 1, 64);
            rs += __shfl_xor(rs, 2, 64);
            rs += __shfl_xor(rs, 4, 64);
            rs += __shfl_xor(rs, 8, 64);
            if (lanelo == 0) {
                const int row = wm * 64 + fi * 16 + quad * 4 + r;
                red[row * 2 + wn] = rs;
            }
        }
    __syncthreads();
    if (tid < 128)
        partial[(size_t)nt * M_ + row0 + tid] = red[tid * 2] + red[tid * 2 + 1];
}

// ---------------------------------------------------------------------------
// Kernel 3: per-batch softmax over S=1024 (sum of 4 partials)
// ---------------------------------------------------------------------------
__global__ __launch_bounds__(256) void softmax_kernel(
    const float* __restrict__ partial, float* __restrict__ out)
{
    const int b = blockIdx.x;
    const int tid = threadIdx.x;
    float val[4];
    float lmax = -3.0e38f;
    #pragma unroll
    for (int q = 0; q < 4; ++q) {
        const int idx = b * S_ + tid + 256 * q;
        float sum = partial[idx] + partial[M_ + idx] + partial[2 * M_ + idx] +
                    partial[3 * M_ + idx];
        val[q] = sum;
        lmax = fmaxf(lmax, sum);
    }
    #pragma unroll
    for (int off = 32; off > 0; off >>= 1)
        lmax = fmaxf(lmax, __shfl_down(lmax, off, 64));
    __shared__ float wmax[4];
    if ((tid & 63) == 0) wmax[tid >> 6] = lmax;
    __syncthreads();
    const float gmax = fmaxf(fmaxf(wmax[0], wmax[1]), fmaxf(wmax[2], wmax[3]));
    float lsum = 0.0f;
    #pragma unroll
    for (int q = 0; q < 4; ++q) {
        val[q] = expf(val[q] - gmax);
        lsum += val[q];
    }
    #pragma unroll
    for (int off = 32; off > 0; off >>= 1)
        lsum += __shfl_down(lsum, off, 64);
    __shared__ float wsum[4];
    if ((tid & 63) == 0) wsum[tid >> 6] = lsum;
    __syncthreads();
    const float inv = 1.0f / (wsum[0] + wsum[1] + wsum[2] + wsum[3]);
    #pragma unroll
    for (int q = 0; q < 4; ++q)
        out[b * S_ + tid + 256 * q] = val[q] * inv;
}

// ---------------------------------------------------------------------------
extern "C" void kernel_launch(void* const* d_in, const int* in_sizes, int n_in,
                              void* d_out, int out_size, void* d_ws, size_t ws_size,
                              hipStream_t stream) {
    const float* hidden = (const float*)d_in[0];
    const float* EO     = (const float*)d_in[1];
    const float* W      = (const float*)d_in[2];
    const float* bias   = (const float*)d_in[3];
    const float* v      = (const float*)d_in[4];
    float* out          = (float*)d_out;

    float* hb      = (float*)d_ws;                       // 16384 floats
    float* partial = hb + B_ * H_;                       // 131072 floats
    unsigned short* Wth = (unsigned short*)(partial + 4 * M_);
    unsigned short* Wtl = Wth + (size_t)H_ * K_;

    prep_kernel<<<768, 256, 0, stream>>>(hidden, W, bias, hb, Wth, Wtl);
    gemm_fused<<<dim3(4, M_ / 128), 256, 0, stream>>>(EO, Wth, Wtl, hb, v, partial);
    softmax_kernel<<<B_, 256, 0, stream>>>(partial, out);
}